// Round 15
// baseline (292.149 us; speedup 1.0000x reference)
//
#include <hip/hip_runtime.h>

constexpr int B = 16, N = 128, D = 128, DN0 = 64, DE0 = 16;

typedef _Float16 half8 __attribute__((ext_vector_type(8)));
typedef _Float16 half4 __attribute__((ext_vector_type(4)));
typedef float floatx4 __attribute__((ext_vector_type(4)));
typedef float floatx16 __attribute__((ext_vector_type(16)));

// async 16B global->LDS. msg0/T2 global layout is cell-swizzled
// (16B cell g of row j stored at g^(j&15)) so linear copies land
// conflict-free in LDS.
__device__ __forceinline__ void gld16(const _Float16* g, _Float16* l) {
  __builtin_amdgcn_global_load_lds(
      (const __attribute__((address_space(1))) void*)g,
      (__attribute__((address_space(3))) void*)l, 16, 0, 0);
}

// ---------------------------------------------------------------------------
// K1: merged prep.
//  bid < 2048           : xi0/xj0 row precompute (256 thr, output split)
//  2048..2175 (128 blk) : weT_l[c][k] = (fp16) w_msg_l[2D+k][c], l=1,2
//  2176..2271 ( 96 blk) : wn0T[c*192+k] = wn0[k*128+c]          (tail GEMV)
//  2272..2399 (128 blk) : wn1T[c*256+k] = wn1[k*128+c]
//  2400..2655 (256 blk) : wm1iT/wm1jT/wm2iT/wm2jT (128x128 each, transposed)
// Transposed fp32 weight columns turn the fused node tails' column-strided
// scalar loads into fully-unrolled contiguous float4 loads (R14: those tails
// cost k_mid +22 us at 2 blocks/CU with no TLP to hide L2 latency).
// ---------------------------------------------------------------------------
__global__ __launch_bounds__(256) void k_pre(
    const float* __restrict__ x, const float* __restrict__ wm0,
    const float* __restrict__ bm0, const float* __restrict__ wm1,
    const float* __restrict__ wm2, const float* __restrict__ wn0,
    const float* __restrict__ wn1,
    float* __restrict__ xi0, float* __restrict__ xj0,
    _Float16* __restrict__ weT1, _Float16* __restrict__ weT2,
    float* __restrict__ wn0T, float* __restrict__ wn1T,
    float* __restrict__ wm1iT, float* __restrict__ wm1jT,
    float* __restrict__ wm2iT, float* __restrict__ wm2jT) {
  const int bid = blockIdx.x;
  const int t = threadIdx.x;
  if (bid < B * N) {
    const int row = bid;
    const int half = t >> 7, c = t & 127;
    __shared__ float xr[DN0];
    if (t < DN0) xr[t] = x[(size_t)row * DN0 + t];
    __syncthreads();
    float a = half ? 0.f : bm0[c];
    const float* wb = wm0 + half * DN0 * D;
    #pragma unroll 8
    for (int k = 0; k < DN0; ++k) a = fmaf(xr[k], wb[k * D + c], a);
    (half ? xj0 : xi0)[(size_t)row * D + c] = a;
  } else if (bid < B * N + 128) {
    const int g = (bid - B * N) * 256 + t;   // 0..32767
    const int layer = g >> 14;
    const int rem = g & 16383;               // = c*D + k
    const int c = rem >> 7, k = rem & 127;
    const float* src = layer ? wm2 : wm1;
    _Float16* dst = layer ? weT2 : weT1;
    dst[rem] = (_Float16)src[(2 * D + k) * D + c];
  } else if (bid < B * N + 224) {            // wn0T (96 blocks)
    const int g = (bid - (B * N + 128)) * 256 + t;   // 0..24575
    const int c = g / 192, k = g % 192;
    wn0T[g] = wn0[k * D + c];
  } else if (bid < B * N + 352) {            // wn1T (128 blocks)
    const int g = (bid - (B * N + 224)) * 256 + t;   // 0..32767
    const int c = g >> 8, k = g & 255;
    wn1T[g] = wn1[k * D + c];
  } else {                                   // wm1iT/jT, wm2iT/jT (256 blocks)
    const int g = (bid - (B * N + 352)) * 256 + t;   // 0..65535
    const int sel = g >> 14;
    const int rem = g & 16383;
    const int c = rem >> 7, k = rem & 127;
    float v;
    float* dst;
    if (sel == 0)      { v = wm1[k * D + c];        dst = wm1iT; }
    else if (sel == 1) { v = wm1[(D + k) * D + c];  dst = wm1jT; }
    else if (sel == 2) { v = wm2[k * D + c];        dst = wm2iT; }
    else               { v = wm2[(D + k) * D + c];  dst = wm2jT; }
    dst[rem] = v;
  }
}

// ---------------------------------------------------------------------------
// K2: layer-0 edge kernel + fused node0. Thread map matches k_fin:
// c8=(t&15)*8, jr=t>>4, j=16p+jr. msg0 half8 stores swizzled, masked.
// Tails use transposed float4 weight columns (contiguous, fully unrolled).
// sIn0[192] = {x0(64), agg0(128)} matches wn0's k-order.
// ---------------------------------------------------------------------------
__global__ __launch_bounds__(256) void k_edge0(
    const int* __restrict__ ei, const float* __restrict__ eattr,
    const float* __restrict__ wm0, const float* __restrict__ x0,
    const float* __restrict__ xi0, const float* __restrict__ xj0,
    const float* __restrict__ wn0T, const float* __restrict__ bn0,
    const float* __restrict__ wm1iT, const float* __restrict__ wm1jT,
    const float* __restrict__ bm1,
    _Float16* __restrict__ msg0, float* __restrict__ x1,
    float* __restrict__ xi1, float* __restrict__ xj1) {
  const int row = blockIdx.x;
  const int b = row >> 7;
  const int t = threadIdx.x;
  const int c8 = (t & 15) * 8, jr = t >> 4;

  __shared__ float eb[N * 20];          // e_row [j][k] pad 20; aliased by hp
  __shared__ float w_t[DE0][D];
  __shared__ float amask[N];
  __shared__ float xi_r[D];
  __shared__ float sIn0[192];           // {x0, agg0}
  __shared__ float sPart[2][D], sX1[D];
  float* hp = eb;                       // [16][16][8] after matmul (8 KB)

  const float4* esrc = (const float4*)(eattr + (size_t)row * N * DE0);
  const float4* wsrc = (const float4*)(wm0 + 2 * DN0 * D);
  #pragma unroll
  for (int u = 0; u < 2; ++u) {
    const int idx4 = u * 256 + t;
    const int j = idx4 >> 2;
    const int k4 = (idx4 & 3) * 4;
    *(float4*)&eb[j * 20 + k4] = esrc[idx4];
    ((float4*)&w_t[0][0])[idx4] = wsrc[idx4];
  }
  if (t < N) {
    amask[t] = (float)ei[(size_t)row * N + t];
    xi_r[t] = xi0[(size_t)row * D + t];
  } else if (t < N + DN0) {
    sIn0[t - N] = x0[(size_t)row * DN0 + (t - N)];
  }
  __syncthreads();

  // --- K=16 matmul: acc[p][q] over j=16p+jr, c=c8+q ---
  float acc[8][8] = {};
  #pragma unroll 4
  for (int k = 0; k < DE0; ++k) {
    float av[8];
    #pragma unroll
    for (int p = 0; p < 8; ++p) av[p] = eb[(16 * p + jr) * 20 + k];
    const floatx4 wv0 = *(const floatx4*)&w_t[k][c8];
    const floatx4 wv1 = *(const floatx4*)&w_t[k][c8 + 4];
    #pragma unroll
    for (int p = 0; p < 8; ++p)
      #pragma unroll
      for (int q = 0; q < 4; ++q) {
        acc[p][q]     = fmaf(av[p], wv0[q], acc[p][q]);
        acc[p][4 + q] = fmaf(av[p], wv1[q], acc[p][4 + q]);
      }
  }

  // --- epilogue: relu+mask, half8 store (swizzled, unmasked only), agg ---
  float acc8[8] = {};
  const float* xjb = xj0 + (size_t)b * N * D;
  _Float16* mrow = msg0 + (size_t)row * N * D;
  const floatx4 xiv0 = *(const floatx4*)&xi_r[c8];
  const floatx4 xiv1 = *(const floatx4*)&xi_r[c8 + 4];
  #pragma unroll
  for (int p = 0; p < 8; ++p) {
    const int j = 16 * p + jr;
    const float am = amask[j];
    const floatx4 xjv0 = *(const floatx4*)&xjb[j * D + c8];
    const floatx4 xjv1 = *(const floatx4*)&xjb[j * D + c8 + 4];
    half8 hv;
    #pragma unroll
    for (int q = 0; q < 4; ++q) {
      float v0 = fmaxf(xiv0[q] + xjv0[q] + acc[p][q], 0.f) * am;
      float v1 = fmaxf(xiv1[q] + xjv1[q] + acc[p][4 + q], 0.f) * am;
      hv[q] = (_Float16)v0;
      hv[4 + q] = (_Float16)v1;
      acc8[q] += v0;
      acc8[4 + q] += v1;
    }
    if (am != 0.f)
      *(half8*)&mrow[j * D + (((t & 15) ^ jr) << 3)] = hv;
  }

  __syncthreads();                      // eb reads done -> safe to alias hp
  #pragma unroll
  for (int q = 0; q < 8; ++q) hp[(jr * 16 + (t & 15)) * 8 + q] = acc8[q];
  __syncthreads();
  if (t < D) {
    float s = 0.f;
    #pragma unroll
    for (int g = 0; g < 16; ++g) s += hp[(g * 16 + (t >> 3)) * 8 + (t & 7)];
    sIn0[DN0 + t] = s;                  // agg0
  }
  __syncthreads();

  // --- fused node0: contiguous float4 weight columns, k-split 2x96 ---
  const int half = t >> 7, c = t & 127;
  {
    float a = half ? 0.f : bn0[c];
    const float* wcol = wn0T + c * 192 + half * 96;
    const float* xin = sIn0 + half * 96;
    #pragma unroll
    for (int k4 = 0; k4 < 24; ++k4) {
      const floatx4 wv = *(const floatx4*)&wcol[4 * k4];
      a = fmaf(xin[4 * k4 + 0], wv[0], a);
      a = fmaf(xin[4 * k4 + 1], wv[1], a);
      a = fmaf(xin[4 * k4 + 2], wv[2], a);
      a = fmaf(xin[4 * k4 + 3], wv[3], a);
    }
    sPart[half][c] = a;
  }
  __syncthreads();
  if (t < D) {
    const float v = fmaxf(sPart[0][t] + sPart[1][t], 0.f);
    x1[(size_t)row * D + t] = v;
    sX1[t] = v;
  }
  __syncthreads();

  // --- xi1/xj1 split by output (xi1 carries bm1), float4 columns ---
  {
    float aa = half ? 0.f : bm1[c];
    const float* wcol = (half ? wm1jT : wm1iT) + c * 128;
    #pragma unroll
    for (int k4 = 0; k4 < 32; ++k4) {
      const floatx4 wv = *(const floatx4*)&wcol[4 * k4];
      aa = fmaf(sX1[4 * k4 + 0], wv[0], aa);
      aa = fmaf(sX1[4 * k4 + 1], wv[1], aa);
      aa = fmaf(sX1[4 * k4 + 2], wv[2], aa);
      aa = fmaf(sX1[4 * k4 + 3], wv[3], aa);
    }
    (half ? xj1 : xi1)[(size_t)row * D + c] = aa;
  }
}

// ---------------------------------------------------------------------------
// K4: fused layer-1+2 edge kernel + fused node1 tail. (256,2), MFMA
// 32x32x16; wave w owns c-tile [32w,32w+32). agg1 never leaves LDS
// (sIn[256] = {x1, agg1} matches wn1 k-order); tails use transposed float4
// weight columns. Masked copy-out. C/D layout (m74/m101): col(j)=lane&31,
// row(c)=(reg&3)+8*(reg>>2)+4*(lane>>5).
// ---------------------------------------------------------------------------
__global__ __launch_bounds__(256, 2) void k_mid(
    const int* __restrict__ ei, const _Float16* __restrict__ weT1,
    const _Float16* __restrict__ weT2,
    const float* __restrict__ xi, const float* __restrict__ xj,
    const float* __restrict__ x1,
    const float* __restrict__ wn1T, const float* __restrict__ bn1,
    const float* __restrict__ wm2iT, const float* __restrict__ wm2jT,
    const float* __restrict__ bm2,
    _Float16* __restrict__ em,          // in: msg0 (swizzled), out: T2
    float* __restrict__ xi2, float* __restrict__ xj2) {
  const int row = blockIdx.x;           // 2048
  const int b = row >> 7;
  const int t = threadIdx.x;
  const int w = t >> 6;                 // c-tile base 32w
  const int lane = t & 63;
  const int l31 = lane & 31;
  const int l15 = lane & 15;
  const int hl = lane >> 5;             // k-half; c offset 4*hl

  __shared__ _Float16 sE[N * D];        // 32 KB, swizzled rows
  __shared__ float sMask[N];
  __shared__ float sIn[2 * D];          // {x1, agg1}
  __shared__ float sPart[2][D], sX2[D];

  // --- async-stage msg0 row (linear copy of swizzled layout) ---
  const _Float16* gsrc = em + (size_t)row * N * D;
  #pragma unroll
  for (int u = 0; u < 8; ++u) {
    const int seg = (u * 4 + w) * 512;  // wave-uniform base, 1 KB per instr
    gld16(gsrc + seg + lane * 8, &sE[seg]);
  }

  // --- pass-1 weight frags: A[m=l31][k=16ks+8hl+e] ---
  half8 a1[8];
  #pragma unroll
  for (int ks = 0; ks < 8; ++ks)
    a1[ks] = *(const half8*)(weT1 + (32 * w + l31) * D + 16 * ks + 8 * hl);

  // --- per-lane invariants (overlap staging) ---
  floatx4 xiv[4];
  #pragma unroll
  for (int g = 0; g < 4; ++g)
    xiv[g] = *(const floatx4*)&xi[(size_t)row * D + 32 * w + 8 * g + 4 * hl];
  if (t < N) sMask[t] = (float)ei[(size_t)row * N + t];
  else if (t < N + D) sIn[t - N] = x1[(size_t)row * D + (t - N)];

  __syncthreads();                      // drains gld16; sMask/sIn visible

  float am[4];
  #pragma unroll
  for (int jt = 0; jt < 4; ++jt) am[jt] = sMask[32 * jt + l31];

  // --- pass 1: T1[c][j] = sum_k We1T[c][k] msg0[j][k] ---
  const floatx16 vzero = {0.f,0.f,0.f,0.f,0.f,0.f,0.f,0.f,
                          0.f,0.f,0.f,0.f,0.f,0.f,0.f,0.f};
  floatx16 acc[4];
  #pragma unroll
  for (int jt = 0; jt < 4; ++jt) acc[jt] = vzero;
  #pragma unroll
  for (int ks = 0; ks < 8; ++ks)
    #pragma unroll
    for (int jt = 0; jt < 4; ++jt) {
      const half8 bv = *(const half8*)
          &sE[(32 * jt + l31) * D + (((2 * ks + hl) ^ l15) << 3)];
      acc[jt] = __builtin_amdgcn_mfma_f32_32x32x16_f16(a1[ks], bv, acc[jt], 0, 0, 0);
    }

  __syncthreads();                      // all pass-1 reads complete

  // --- epilogue 1: msg1 -> hacc, e_mid RMW in LDS ---
  const float* xjb = xj + (size_t)b * N * D;
  floatx4 hacc[4];
  #pragma unroll
  for (int g = 0; g < 4; ++g) hacc[g] = (floatx4){0.f, 0.f, 0.f, 0.f};
  #pragma unroll
  for (int jt = 0; jt < 4; ++jt) {
    const int j = 32 * jt + l31;        // j&15 == l15
    #pragma unroll
    for (int g = 0; g < 4; ++g) {
      const int cofs = 32 * w + 8 * g + 4 * hl;
      const int hidx = j * D + (((4 * w + g) ^ l15) << 3) + 4 * hl;
      const floatx4 xjv = *(const floatx4*)&xjb[j * D + cofs];
      const half4 m0 = *(const half4*)&sE[hidx];
      half4 mid;
      floatx4 m1;
      #pragma unroll
      for (int r = 0; r < 4; ++r) {
        const float v = xiv[g][r] + xjv[r] + acc[jt][4 * g + r];
        m1[r] = fmaxf(v, 0.f) * am[jt];
        mid[r] = (_Float16)(0.5f * ((float)m0[r] + m1[r]));
      }
      *(half4*)&sE[hidx] = mid;
      hacc[g] += m1;
    }
  }

  // agg1 -> sIn[128..]: butterfly over l31 spans all 128 j
  #pragma unroll
  for (int m = 1; m < 32; m <<= 1)
    #pragma unroll
    for (int g = 0; g < 4; ++g)
      #pragma unroll
      for (int r = 0; r < 4; ++r)
        hacc[g][r] += __shfl_xor(hacc[g][r], m, 64);
  if (l31 == 0) {
    #pragma unroll
    for (int g = 0; g < 4; ++g)
      *(floatx4*)&sIn[D + 32 * w + 8 * g + 4 * hl] = hacc[g];
  }

  // pass-2 weights (a1 dead -> regs reusable)
  half8 a2[8];
  #pragma unroll
  for (int ks = 0; ks < 8; ++ks)
    a2[ks] = *(const half8*)(weT2 + (32 * w + l31) * D + 16 * ks + 8 * hl);

  __syncthreads();                      // e_mid + sIn visible to all waves

  // --- pass 2: T2[c][j] = sum_k We2T[c][k] e_mid[j][k] ---
  #pragma unroll
  for (int jt = 0; jt < 4; ++jt) acc[jt] = vzero;
  #pragma unroll
  for (int ks = 0; ks < 8; ++ks)
    #pragma unroll
    for (int jt = 0; jt < 4; ++jt) {
      const half8 bv = *(const half8*)
          &sE[(32 * jt + l31) * D + (((2 * ks + hl) ^ l15) << 3)];
      acc[jt] = __builtin_amdgcn_mfma_f32_32x32x16_f16(a2[ks], bv, acc[jt], 0, 0, 0);
    }

  __syncthreads();                      // all pass-2 reads complete

  // --- deposit T2 into sE (same cell mapping) ---
  #pragma unroll
  for (int jt = 0; jt < 4; ++jt) {
    const int j = 32 * jt + l31;
    #pragma unroll
    for (int g = 0; g < 4; ++g) {
      const int hidx = j * D + (((4 * w + g) ^ l15) << 3) + 4 * hl;
      half4 tv;
      #pragma unroll
      for (int r = 0; r < 4; ++r) tv[r] = (_Float16)acc[jt][4 * g + r];
      *(half4*)&sE[hidx] = tv;
    }
  }

  __syncthreads();                      // T2 complete in LDS

  // --- copy-out, unmasked j rows only (swizzled layout preserved) ---
  uint4* gdst = (uint4*)(em + (size_t)row * N * D);
  const uint4* ls = (const uint4*)sE;
  #pragma unroll
  for (int u = 0; u < 8; ++u) {
    const int idx4 = u * 256 + t;
    const int j = u * 16 + (t >> 4);
    if (sMask[j] != 0.f) gdst[idx4] = ls[idx4];
  }

  // --- fused node1: x2 = 0.5*(x1 + relu(x1@Wx1 + agg1@Wa1 + bn1)) ---
  const int half = t >> 7, c = t & 127;
  {
    float a = half ? 0.f : bn1[c];
    const float* wcol = wn1T + c * 256 + half * 128;
    const float* xin = sIn + half * 128;
    #pragma unroll
    for (int k4 = 0; k4 < 32; ++k4) {
      const floatx4 wv = *(const floatx4*)&wcol[4 * k4];
      a = fmaf(xin[4 * k4 + 0], wv[0], a);
      a = fmaf(xin[4 * k4 + 1], wv[1], a);
      a = fmaf(xin[4 * k4 + 2], wv[2], a);
      a = fmaf(xin[4 * k4 + 3], wv[3], a);
    }
    sPart[half][c] = a;
  }
  __syncthreads();
  if (t < D)
    sX2[t] = 0.5f * (sIn[t] + fmaxf(sPart[0][t] + sPart[1][t], 0.f));
  __syncthreads();
  {
    float aa = half ? 0.f : bm2[c];
    const float* wcol = (half ? wm2jT : wm2iT) + c * 128;
    #pragma unroll
    for (int k4 = 0; k4 < 32; ++k4) {
      const floatx4 wv = *(const floatx4*)&wcol[4 * k4];
      aa = fmaf(sX2[4 * k4 + 0], wv[0], aa);
      aa = fmaf(sX2[4 * k4 + 1], wv[1], aa);
      aa = fmaf(sX2[4 * k4 + 2], wv[2], aa);
      aa = fmaf(sX2[4 * k4 + 3], wv[3], aa);
    }
    (half ? xj2 : xi2)[(size_t)row * D + c] = aa;
  }
}

// ---------------------------------------------------------------------------
// K6: final layer streaming: msg2 = relu(xi2 + xj2 + T2)*A; rowsum over j.
// Masked j rows skipped entirely (contribution 0; saves their 256 B loads).
// ---------------------------------------------------------------------------
__global__ __launch_bounds__(256) void k_fin(
    const int* __restrict__ ei, const _Float16* __restrict__ t2,
    const float* __restrict__ xi, const float* __restrict__ xj,
    float* __restrict__ rowsum) {
  const int row = blockIdx.x;
  const int b = row >> 7;
  const int t = threadIdx.x;
  const int c8 = (t & 15) * 8, jr = t >> 4;

  __shared__ float sMask[N];
  __shared__ float hp[16][16][8];
  if (t < N) sMask[t] = (float)ei[(size_t)row * N + t];
  float xiv[8];
  *(floatx4*)&xiv[0] = *(const floatx4*)&xi[row * D + c8];
  *(floatx4*)&xiv[4] = *(const floatx4*)&xi[row * D + c8 + 4];
  __syncthreads();

  const _Float16* src = t2 + (size_t)row * N * D;
  const float* xjb = xj + (size_t)b * N * D;
  float acc8[8] = {};
  #pragma unroll
  for (int u = 0; u < 8; ++u) {
    const int j = u * 16 + jr;           // j&15 == jr
    if (sMask[j] != 0.f) {
      const half8 tv = *(const half8*)(src + j * D + (((t & 15) ^ jr) << 3));
      const floatx4 xj0 = *(const floatx4*)&xjb[j * D + c8];
      const floatx4 xj1 = *(const floatx4*)&xjb[j * D + c8 + 4];
      #pragma unroll
      for (int r = 0; r < 4; ++r) {
        acc8[r]     += fmaxf(xiv[r] + xj0[r] + (float)tv[r], 0.f);
        acc8[4 + r] += fmaxf(xiv[4 + r] + xj1[r] + (float)tv[4 + r], 0.f);
      }
    }
  }
  #pragma unroll
  for (int k = 0; k < 8; ++k) hp[jr][t & 15][k] = acc8[k];
  __syncthreads();
  if (t < D) {
    float s = 0.f;
    #pragma unroll
    for (int g = 0; g < 16; ++g) s += hp[g][t >> 3][t & 7];
    rowsum[row * D + t] = s;
  }
}

// ---------------------------------------------------------------------------
// K7: head MLP. 16 blocks.
// ---------------------------------------------------------------------------
__global__ __launch_bounds__(128) void k_head(
    const float* __restrict__ rowsum,
    const float* __restrict__ w1, const float* __restrict__ b1,
    const float* __restrict__ w2, const float* __restrict__ b2,
    const float* __restrict__ w3, const float* __restrict__ b3,
    float* __restrict__ out) {
  const int b = blockIdx.x;
  const int c = threadIdx.x;
  __shared__ float hr[D], h1r[D], h2r[D];
  const float* rs = rowsum + (size_t)b * N * D;
  float s = 0.f;
  for (int i = 0; i < N; ++i) s += rs[i * D + c];
  hr[c] = s * (1.f / (N * N));
  __syncthreads();
  float a = b1[c];
  #pragma unroll 8
  for (int k = 0; k < D; ++k) a = fmaf(hr[k], w1[k * D + c], a);
  h1r[c] = fmaxf(a, 0.f);
  __syncthreads();
  a = b2[c];
  #pragma unroll 8
  for (int k = 0; k < D; ++k) a = fmaf(h1r[k], w2[k * D + c], a);
  h2r[c] = fmaxf(a, 0.f);
  __syncthreads();
  hr[c] = h2r[c] * w3[c];
  __syncthreads();
  if (c == 0) {
    float s2 = b3[0];
    for (int k = 0; k < D; ++k) s2 += hr[k];
    out[b] = s2;
  }
}

// ---------------------------------------------------------------------------
extern "C" void kernel_launch(void* const* d_in, const int* in_sizes, int n_in,
                              void* d_out, int out_size, void* d_ws, size_t ws_size,
                              hipStream_t stream) {
  const int*   ei  = (const int*)d_in[0];
  const float* x0  = (const float*)d_in[1];
  const float* ea  = (const float*)d_in[2];
  const float* wm0 = (const float*)d_in[3];
  const float* bm0 = (const float*)d_in[4];
  const float* wn0 = (const float*)d_in[5];
  const float* bn0 = (const float*)d_in[6];
  const float* wm1 = (const float*)d_in[7];
  const float* bm1 = (const float*)d_in[8];
  const float* wn1 = (const float*)d_in[9];
  const float* bn1 = (const float*)d_in[10];
  const float* wm2 = (const float*)d_in[11];
  const float* bm2 = (const float*)d_in[12];
  const float* wh1 = (const float*)d_in[15];
  const float* bh1 = (const float*)d_in[16];
  const float* wh2 = (const float*)d_in[17];
  const float* bh2 = (const float*)d_in[18];
  const float* wh3 = (const float*)d_in[19];
  const float* bh3 = (const float*)d_in[20];
  float* out = (float*)d_out;

  _Float16* msg0h = (_Float16*)d_ws;                 // [B,N,N,D] fp16: msg0 -> T2
  _Float16* weT1  = msg0h + (size_t)B * N * N * D;
  _Float16* weT2  = weT1 + D * D;
  float* f = (float*)(weT2 + D * D);
  size_t off = 0;
  const size_t R = (size_t)B * N * D;
  float* wn0T  = f + off; off += 128 * 192;
  float* wn1T  = f + off; off += 128 * 256;
  float* wm1iT = f + off; off += D * D;
  float* wm1jT = f + off; off += D * D;
  float* wm2iT = f + off; off += D * D;
  float* wm2jT = f + off; off += D * D;
  float* xi0  = f + off; off += R;
  float* xj0  = f + off; off += R;
  float* x1   = f + off; off += R;
  float* xi1  = f + off; off += R;
  float* xj1  = f + off; off += R;
  float* xi2  = f + off; off += R;
  float* xj2  = f + off; off += R;
  float* rsum = f + off; off += R;

  const int rows = B * N;   // 2048
  k_pre  <<<rows + 608, 256, 0, stream>>>(x0, wm0, bm0, wm1, wm2, wn0, wn1,
                                          xi0, xj0, weT1, weT2,
                                          wn0T, wn1T, wm1iT, wm1jT,
                                          wm2iT, wm2jT);
  k_edge0<<<rows, 256, 0, stream>>>(ei, ea, wm0, x0, xi0, xj0,
                                    wn0T, bn0, wm1iT, wm1jT, bm1,
                                    msg0h, x1, xi1, xj1);
  k_mid  <<<rows, 256, 0, stream>>>(ei, weT1, weT2, xi1, xj1, x1,
                                    wn1T, bn1, wm2iT, wm2jT, bm2,
                                    msg0h, xi2, xj2);
  k_fin  <<<rows, 256, 0, stream>>>(ei, msg0h, xi2, xj2, rsum);
  k_head <<<B,    128, 0, stream>>>(rsum, wh1, bh1, wh2, bh2, wh3, bh3, out);
}

// Round 16
// 222.593 us; speedup vs baseline: 1.3125x; 1.3125x over previous
//
#include <hip/hip_runtime.h>

constexpr int B = 16, N = 128, D = 128, DN0 = 64, DE0 = 16;

typedef _Float16 half8 __attribute__((ext_vector_type(8)));
typedef _Float16 half4 __attribute__((ext_vector_type(4)));
typedef float floatx4 __attribute__((ext_vector_type(4)));
typedef float floatx16 __attribute__((ext_vector_type(16)));

// async 16B global->LDS. msg0/T2 global layout is cell-swizzled
// (16B cell g of row j stored at g^(j&15)) so linear copies land
// conflict-free in LDS.
__device__ __forceinline__ void gld16(const _Float16* g, _Float16* l) {
  __builtin_amdgcn_global_load_lds(
      (const __attribute__((address_space(1))) void*)g,
      (__attribute__((address_space(3))) void*)l, 16, 0, 0);
}

// ---------------------------------------------------------------------------
// K1: merged prep. bid < 2048: xi0/xj0 row precompute (256 thr, output split).
// bid >= 2048 (128 blocks): WeT_l[c][k] = (fp16) w_msg_l[2D+k][c], l=1,2.
// NOTE (R15 lesson): tail GEMV weights stay in k-major layout — w[k*D+c] is
// coalesced ACROSS THE WAVE at each k; per-thread-contiguous transposed
// columns anti-coalesce (64 lanes -> 64 cache lines) and cost 2x (R15).
// ---------------------------------------------------------------------------
__global__ __launch_bounds__(256) void k_pre(
    const float* __restrict__ x, const float* __restrict__ wm0,
    const float* __restrict__ bm0, const float* __restrict__ wm1,
    const float* __restrict__ wm2,
    float* __restrict__ xi0, float* __restrict__ xj0,
    _Float16* __restrict__ weT1, _Float16* __restrict__ weT2) {
  const int bid = blockIdx.x;
  const int t = threadIdx.x;
  if (bid < B * N) {
    const int row = bid;
    const int half = t >> 7, c = t & 127;
    __shared__ float xr[DN0];
    if (t < DN0) xr[t] = x[(size_t)row * DN0 + t];
    __syncthreads();
    float a = half ? 0.f : bm0[c];
    const float* wb = wm0 + half * DN0 * D;
    #pragma unroll 32
    for (int k = 0; k < DN0; ++k) a = fmaf(xr[k], wb[k * D + c], a);
    (half ? xj0 : xi0)[(size_t)row * D + c] = a;
  } else {
    const int g = (bid - B * N) * 256 + t;   // 0..32767
    const int layer = g >> 14;
    const int rem = g & 16383;               // = c*D + k
    const int c = rem >> 7, k = rem & 127;
    const float* src = layer ? wm2 : wm1;
    _Float16* dst = layer ? weT2 : weT1;
    dst[rem] = (_Float16)src[(2 * D + k) * D + c];
  }
}

// ---------------------------------------------------------------------------
// K2: layer-0 edge kernel + fused node0 (R12/R14 proven shape). Thread map
// matches k_fin: c8=(t&15)*8, jr=t>>4, j=16p+jr. msg0 half8 stores swizzled,
// masked. Tail unroll 8->32: 4x outstanding L2-hot weight loads (the tails
// are load-latency bound at low occupancy, not pattern-bound — R15 PM).
// ---------------------------------------------------------------------------
__global__ __launch_bounds__(256) void k_edge0(
    const int* __restrict__ ei, const float* __restrict__ eattr,
    const float* __restrict__ wm0, const float* __restrict__ x0,
    const float* __restrict__ xi0, const float* __restrict__ xj0,
    const float* __restrict__ wn0, const float* __restrict__ bn0,
    const float* __restrict__ wm1, const float* __restrict__ bm1,
    _Float16* __restrict__ msg0, float* __restrict__ x1,
    float* __restrict__ xi1, float* __restrict__ xj1) {
  const int row = blockIdx.x;
  const int b = row >> 7;
  const int t = threadIdx.x;
  const int c8 = (t & 15) * 8, jr = t >> 4;

  __shared__ float eb[N * 20];          // e_row [j][k] pad 20; aliased by hp
  __shared__ float w_t[DE0][D];
  __shared__ float amask[N];
  __shared__ float xi_r[D];
  __shared__ float sX0[DN0], sAgg[D], sPart[2][D], sX1[D];
  float* hp = eb;                       // [16][16][8] after matmul (8 KB)

  const float4* esrc = (const float4*)(eattr + (size_t)row * N * DE0);
  const float4* wsrc = (const float4*)(wm0 + 2 * DN0 * D);
  #pragma unroll
  for (int u = 0; u < 2; ++u) {
    const int idx4 = u * 256 + t;
    const int j = idx4 >> 2;
    const int k4 = (idx4 & 3) * 4;
    *(float4*)&eb[j * 20 + k4] = esrc[idx4];
    ((float4*)&w_t[0][0])[idx4] = wsrc[idx4];
  }
  if (t < N) {
    amask[t] = (float)ei[(size_t)row * N + t];
    xi_r[t] = xi0[(size_t)row * D + t];
  } else if (t < N + DN0) {
    sX0[t - N] = x0[(size_t)row * DN0 + (t - N)];
  }
  __syncthreads();

  // --- K=16 matmul: acc[p][q] over j=16p+jr, c=c8+q ---
  float acc[8][8] = {};
  #pragma unroll 4
  for (int k = 0; k < DE0; ++k) {
    float av[8];
    #pragma unroll
    for (int p = 0; p < 8; ++p) av[p] = eb[(16 * p + jr) * 20 + k];
    const floatx4 wv0 = *(const floatx4*)&w_t[k][c8];
    const floatx4 wv1 = *(const floatx4*)&w_t[k][c8 + 4];
    #pragma unroll
    for (int p = 0; p < 8; ++p)
      #pragma unroll
      for (int q = 0; q < 4; ++q) {
        acc[p][q]     = fmaf(av[p], wv0[q], acc[p][q]);
        acc[p][4 + q] = fmaf(av[p], wv1[q], acc[p][4 + q]);
      }
  }

  // --- epilogue: relu+mask, half8 store (swizzled, unmasked only), agg ---
  float acc8[8] = {};
  const float* xjb = xj0 + (size_t)b * N * D;
  _Float16* mrow = msg0 + (size_t)row * N * D;
  const floatx4 xiv0 = *(const floatx4*)&xi_r[c8];
  const floatx4 xiv1 = *(const floatx4*)&xi_r[c8 + 4];
  #pragma unroll
  for (int p = 0; p < 8; ++p) {
    const int j = 16 * p + jr;
    const float am = amask[j];
    const floatx4 xjv0 = *(const floatx4*)&xjb[j * D + c8];
    const floatx4 xjv1 = *(const floatx4*)&xjb[j * D + c8 + 4];
    half8 hv;
    #pragma unroll
    for (int q = 0; q < 4; ++q) {
      float v0 = fmaxf(xiv0[q] + xjv0[q] + acc[p][q], 0.f) * am;
      float v1 = fmaxf(xiv1[q] + xjv1[q] + acc[p][4 + q], 0.f) * am;
      hv[q] = (_Float16)v0;
      hv[4 + q] = (_Float16)v1;
      acc8[q] += v0;
      acc8[4 + q] += v1;
    }
    if (am != 0.f)
      *(half8*)&mrow[j * D + (((t & 15) ^ jr) << 3)] = hv;
  }

  __syncthreads();                      // eb reads done -> safe to alias hp
  #pragma unroll
  for (int q = 0; q < 8; ++q) hp[(jr * 16 + (t & 15)) * 8 + q] = acc8[q];
  __syncthreads();
  if (t < D) {
    float s = 0.f;
    #pragma unroll
    for (int g = 0; g < 16; ++g) s += hp[(g * 16 + (t >> 3)) * 8 + (t & 7)];
    sAgg[t] = s;
  }
  __syncthreads();

  // --- fused node0, k-split across 256 threads (2 x 96), unroll 32 ---
  const int half = t >> 7, c = t & 127;
  {
    float a;
    if (half == 0) {
      a = bn0[c];
      #pragma unroll 32
      for (int k = 0; k < DN0; ++k) a = fmaf(sX0[k], wn0[k * D + c], a);
      #pragma unroll
      for (int k = 0; k < 32; ++k) a = fmaf(sAgg[k], wn0[(DN0 + k) * D + c], a);
    } else {
      a = 0.f;
      #pragma unroll 32
      for (int k = 32; k < D; ++k) a = fmaf(sAgg[k], wn0[(DN0 + k) * D + c], a);
    }
    sPart[half][c] = a;
  }
  __syncthreads();
  if (t < D) {
    const float v = fmaxf(sPart[0][t] + sPart[1][t], 0.f);
    x1[(size_t)row * D + t] = v;
    sX1[t] = v;
  }
  __syncthreads();

  // --- xi1/xj1 split by output (xi1 carries bm1), unroll 32 ---
  {
    float aa = half ? 0.f : bm1[c];
    const float* wh = wm1 + half * D * D;
    #pragma unroll 32
    for (int k = 0; k < D; ++k) aa = fmaf(sX1[k], wh[k * D + c], aa);
    (half ? xj1 : xi1)[(size_t)row * D + c] = aa;
  }
}

// ---------------------------------------------------------------------------
// K4: fused layer-1+2 edge kernel + fused node1 tail. (256,2), MFMA
// 32x32x16; wave w owns c-tile [32w,32w+32). agg1 never leaves LDS.
// Tail unroll 8->32 (latency-ILP fix; weights k-major = wave-coalesced).
// Masked copy-out. C/D layout (m74/m101): col(j)=lane&31,
// row(c)=(reg&3)+8*(reg>>2)+4*(lane>>5).
// ---------------------------------------------------------------------------
__global__ __launch_bounds__(256, 2) void k_mid(
    const int* __restrict__ ei, const _Float16* __restrict__ weT1,
    const _Float16* __restrict__ weT2,
    const float* __restrict__ xi, const float* __restrict__ xj,
    const float* __restrict__ x1,
    const float* __restrict__ wn1, const float* __restrict__ bn1,
    const float* __restrict__ wm2, const float* __restrict__ bm2,
    _Float16* __restrict__ em,          // in: msg0 (swizzled), out: T2
    float* __restrict__ xi2, float* __restrict__ xj2) {
  const int row = blockIdx.x;           // 2048
  const int b = row >> 7;
  const int t = threadIdx.x;
  const int w = t >> 6;                 // c-tile base 32w
  const int lane = t & 63;
  const int l31 = lane & 31;
  const int l15 = lane & 15;
  const int hl = lane >> 5;             // k-half; c offset 4*hl

  __shared__ _Float16 sE[N * D];        // 32 KB, swizzled rows
  __shared__ float sMask[N];
  __shared__ float sAgg[D], sX1[D], sPart[2][D], sX2[D];

  // --- async-stage msg0 row (linear copy of swizzled layout) ---
  const _Float16* gsrc = em + (size_t)row * N * D;
  #pragma unroll
  for (int u = 0; u < 8; ++u) {
    const int seg = (u * 4 + w) * 512;  // wave-uniform base, 1 KB per instr
    gld16(gsrc + seg + lane * 8, &sE[seg]);
  }

  // --- pass-1 weight frags: A[m=l31][k=16ks+8hl+e] ---
  half8 a1[8];
  #pragma unroll
  for (int ks = 0; ks < 8; ++ks)
    a1[ks] = *(const half8*)(weT1 + (32 * w + l31) * D + 16 * ks + 8 * hl);

  // --- per-lane invariants (overlap staging) ---
  floatx4 xiv[4];
  #pragma unroll
  for (int g = 0; g < 4; ++g)
    xiv[g] = *(const floatx4*)&xi[(size_t)row * D + 32 * w + 8 * g + 4 * hl];
  if (t < N) sMask[t] = (float)ei[(size_t)row * N + t];
  else if (t < N + D) sX1[t - N] = x1[(size_t)row * D + (t - N)];

  __syncthreads();                      // drains gld16; sMask/sX1 visible

  float am[4];
  #pragma unroll
  for (int jt = 0; jt < 4; ++jt) am[jt] = sMask[32 * jt + l31];

  // --- pass 1: T1[c][j] = sum_k We1T[c][k] msg0[j][k] ---
  const floatx16 vzero = {0.f,0.f,0.f,0.f,0.f,0.f,0.f,0.f,
                          0.f,0.f,0.f,0.f,0.f,0.f,0.f,0.f};
  floatx16 acc[4];
  #pragma unroll
  for (int jt = 0; jt < 4; ++jt) acc[jt] = vzero;
  #pragma unroll
  for (int ks = 0; ks < 8; ++ks)
    #pragma unroll
    for (int jt = 0; jt < 4; ++jt) {
      const half8 bv = *(const half8*)
          &sE[(32 * jt + l31) * D + (((2 * ks + hl) ^ l15) << 3)];
      acc[jt] = __builtin_amdgcn_mfma_f32_32x32x16_f16(a1[ks], bv, acc[jt], 0, 0, 0);
    }

  __syncthreads();                      // all pass-1 reads complete

  // --- epilogue 1: msg1 -> hacc, e_mid RMW in LDS ---
  const float* xjb = xj + (size_t)b * N * D;
  floatx4 hacc[4];
  #pragma unroll
  for (int g = 0; g < 4; ++g) hacc[g] = (floatx4){0.f, 0.f, 0.f, 0.f};
  #pragma unroll
  for (int jt = 0; jt < 4; ++jt) {
    const int j = 32 * jt + l31;        // j&15 == l15
    #pragma unroll
    for (int g = 0; g < 4; ++g) {
      const int cofs = 32 * w + 8 * g + 4 * hl;
      const int hidx = j * D + (((4 * w + g) ^ l15) << 3) + 4 * hl;
      const floatx4 xjv = *(const floatx4*)&xjb[j * D + cofs];
      const half4 m0 = *(const half4*)&sE[hidx];
      half4 mid;
      floatx4 m1;
      #pragma unroll
      for (int r = 0; r < 4; ++r) {
        const float v = xiv[g][r] + xjv[r] + acc[jt][4 * g + r];
        m1[r] = fmaxf(v, 0.f) * am[jt];
        mid[r] = (_Float16)(0.5f * ((float)m0[r] + m1[r]));
      }
      *(half4*)&sE[hidx] = mid;
      hacc[g] += m1;
    }
  }

  // agg1 -> sAgg: butterfly over l31 spans all 128 j
  #pragma unroll
  for (int m = 1; m < 32; m <<= 1)
    #pragma unroll
    for (int g = 0; g < 4; ++g)
      #pragma unroll
      for (int r = 0; r < 4; ++r)
        hacc[g][r] += __shfl_xor(hacc[g][r], m, 64);
  if (l31 == 0) {
    #pragma unroll
    for (int g = 0; g < 4; ++g)
      *(floatx4*)&sAgg[32 * w + 8 * g + 4 * hl] = hacc[g];
  }

  // pass-2 weights (a1 dead -> regs reusable)
  half8 a2[8];
  #pragma unroll
  for (int ks = 0; ks < 8; ++ks)
    a2[ks] = *(const half8*)(weT2 + (32 * w + l31) * D + 16 * ks + 8 * hl);

  __syncthreads();                      // e_mid + sAgg visible to all waves

  // --- pass 2: T2[c][j] = sum_k We2T[c][k] e_mid[j][k] ---
  #pragma unroll
  for (int jt = 0; jt < 4; ++jt) acc[jt] = vzero;
  #pragma unroll
  for (int ks = 0; ks < 8; ++ks)
    #pragma unroll
    for (int jt = 0; jt < 4; ++jt) {
      const half8 bv = *(const half8*)
          &sE[(32 * jt + l31) * D + (((2 * ks + hl) ^ l15) << 3)];
      acc[jt] = __builtin_amdgcn_mfma_f32_32x32x16_f16(a2[ks], bv, acc[jt], 0, 0, 0);
    }

  __syncthreads();                      // all pass-2 reads complete

  // --- deposit T2 into sE (same cell mapping) ---
  #pragma unroll
  for (int jt = 0; jt < 4; ++jt) {
    const int j = 32 * jt + l31;
    #pragma unroll
    for (int g = 0; g < 4; ++g) {
      const int hidx = j * D + (((4 * w + g) ^ l15) << 3) + 4 * hl;
      half4 tv;
      #pragma unroll
      for (int r = 0; r < 4; ++r) tv[r] = (_Float16)acc[jt][4 * g + r];
      *(half4*)&sE[hidx] = tv;
    }
  }

  __syncthreads();                      // T2 complete in LDS

  // --- copy-out, unmasked j rows only (swizzled layout preserved) ---
  uint4* gdst = (uint4*)(em + (size_t)row * N * D);
  const uint4* ls = (const uint4*)sE;
  #pragma unroll
  for (int u = 0; u < 8; ++u) {
    const int idx4 = u * 256 + t;
    const int j = u * 16 + (t >> 4);
    if (sMask[j] != 0.f) gdst[idx4] = ls[idx4];
  }

  // --- fused node1: x2 = 0.5*(x1 + relu(x1@Wx1 + agg1@Wa1 + bn1)) ---
  const int half = t >> 7, c = t & 127;
  {
    float a;
    if (half == 0) {
      a = bn1[c];
      #pragma unroll 32
      for (int k = 0; k < D; ++k) a = fmaf(sX1[k], wn1[k * D + c], a);
    } else {
      a = 0.f;
      #pragma unroll 32
      for (int k = 0; k < D; ++k) a = fmaf(sAgg[k], wn1[(D + k) * D + c], a);
    }
    sPart[half][c] = a;
  }
  __syncthreads();
  if (t < D)
    sX2[t] = 0.5f * (sX1[t] + fmaxf(sPart[0][t] + sPart[1][t], 0.f));
  __syncthreads();
  {
    float aa = half ? 0.f : bm2[c];
    const float* wh = wm2 + half * D * D;
    #pragma unroll 32
    for (int k = 0; k < D; ++k) aa = fmaf(sX2[k], wh[k * D + c], aa);
    (half ? xj2 : xi2)[(size_t)row * D + c] = aa;
  }
}

// ---------------------------------------------------------------------------
// K6: final layer streaming: msg2 = relu(xi2 + xj2 + T2)*A; rowsum over j.
// Masked j rows skipped entirely (contribution 0; saves their 256 B loads).
// ---------------------------------------------------------------------------
__global__ __launch_bounds__(256) void k_fin(
    const int* __restrict__ ei, const _Float16* __restrict__ t2,
    const float* __restrict__ xi, const float* __restrict__ xj,
    float* __restrict__ rowsum) {
  const int row = blockIdx.x;
  const int b = row >> 7;
  const int t = threadIdx.x;
  const int c8 = (t & 15) * 8, jr = t >> 4;

  __shared__ float sMask[N];
  __shared__ float hp[16][16][8];
  if (t < N) sMask[t] = (float)ei[(size_t)row * N + t];
  float xiv[8];
  *(floatx4*)&xiv[0] = *(const floatx4*)&xi[row * D + c8];
  *(floatx4*)&xiv[4] = *(const floatx4*)&xi[row * D + c8 + 4];
  __syncthreads();

  const _Float16* src = t2 + (size_t)row * N * D;
  const float* xjb = xj + (size_t)b * N * D;
  float acc8[8] = {};
  #pragma unroll
  for (int u = 0; u < 8; ++u) {
    const int j = u * 16 + jr;           // j&15 == jr
    if (sMask[j] != 0.f) {
      const half8 tv = *(const half8*)(src + j * D + (((t & 15) ^ jr) << 3));
      const floatx4 xj0 = *(const floatx4*)&xjb[j * D + c8];
      const floatx4 xj1 = *(const floatx4*)&xjb[j * D + c8 + 4];
      #pragma unroll
      for (int r = 0; r < 4; ++r) {
        acc8[r]     += fmaxf(xiv[r] + xj0[r] + (float)tv[r], 0.f);
        acc8[4 + r] += fmaxf(xiv[4 + r] + xj1[r] + (float)tv[4 + r], 0.f);
      }
    }
  }
  #pragma unroll
  for (int k = 0; k < 8; ++k) hp[jr][t & 15][k] = acc8[k];
  __syncthreads();
  if (t < D) {
    float s = 0.f;
    #pragma unroll
    for (int g = 0; g < 16; ++g) s += hp[g][t >> 3][t & 7];
    rowsum[row * D + t] = s;
  }
}

// ---------------------------------------------------------------------------
// K7: head MLP. 16 blocks.
// ---------------------------------------------------------------------------
__global__ __launch_bounds__(128) void k_head(
    const float* __restrict__ rowsum,
    const float* __restrict__ w1, const float* __restrict__ b1,
    const float* __restrict__ w2, const float* __restrict__ b2,
    const float* __restrict__ w3, const float* __restrict__ b3,
    float* __restrict__ out) {
  const int b = blockIdx.x;
  const int c = threadIdx.x;
  __shared__ float hr[D], h1r[D], h2r[D];
  const float* rs = rowsum + (size_t)b * N * D;
  float s = 0.f;
  for (int i = 0; i < N; ++i) s += rs[i * D + c];
  hr[c] = s * (1.f / (N * N));
  __syncthreads();
  float a = b1[c];
  #pragma unroll 8
  for (int k = 0; k < D; ++k) a = fmaf(hr[k], w1[k * D + c], a);
  h1r[c] = fmaxf(a, 0.f);
  __syncthreads();
  a = b2[c];
  #pragma unroll 8
  for (int k = 0; k < D; ++k) a = fmaf(h1r[k], w2[k * D + c], a);
  h2r[c] = fmaxf(a, 0.f);
  __syncthreads();
  hr[c] = h2r[c] * w3[c];
  __syncthreads();
  if (c == 0) {
    float s2 = b3[0];
    for (int k = 0; k < D; ++k) s2 += hr[k];
    out[b] = s2;
  }
}

// ---------------------------------------------------------------------------
extern "C" void kernel_launch(void* const* d_in, const int* in_sizes, int n_in,
                              void* d_out, int out_size, void* d_ws, size_t ws_size,
                              hipStream_t stream) {
  const int*   ei  = (const int*)d_in[0];
  const float* x0  = (const float*)d_in[1];
  const float* ea  = (const float*)d_in[2];
  const float* wm0 = (const float*)d_in[3];
  const float* bm0 = (const float*)d_in[4];
  const float* wn0 = (const float*)d_in[5];
  const float* bn0 = (const float*)d_in[6];
  const float* wm1 = (const float*)d_in[7];
  const float* bm1 = (const float*)d_in[8];
  const float* wn1 = (const float*)d_in[9];
  const float* bn1 = (const float*)d_in[10];
  const float* wm2 = (const float*)d_in[11];
  const float* bm2 = (const float*)d_in[12];
  const float* wh1 = (const float*)d_in[15];
  const float* bh1 = (const float*)d_in[16];
  const float* wh2 = (const float*)d_in[17];
  const float* bh2 = (const float*)d_in[18];
  const float* wh3 = (const float*)d_in[19];
  const float* bh3 = (const float*)d_in[20];
  float* out = (float*)d_out;

  _Float16* msg0h = (_Float16*)d_ws;                 // [B,N,N,D] fp16: msg0 -> T2
  _Float16* weT1  = msg0h + (size_t)B * N * N * D;
  _Float16* weT2  = weT1 + D * D;
  float* f = (float*)(weT2 + D * D);
  size_t off = 0;
  const size_t R = (size_t)B * N * D;
  float* xi0  = f + off; off += R;
  float* xj0  = f + off; off += R;
  float* x1   = f + off; off += R;
  float* xi1  = f + off; off += R;
  float* xj1  = f + off; off += R;
  float* xi2  = f + off; off += R;
  float* xj2  = f + off; off += R;
  float* rsum = f + off; off += R;

  const int rows = B * N;   // 2048
  k_pre  <<<rows + 128, 256, 0, stream>>>(x0, wm0, bm0, wm1, wm2,
                                          xi0, xj0, weT1, weT2);
  k_edge0<<<rows, 256, 0, stream>>>(ei, ea, wm0, x0, xi0, xj0,
                                    wn0, bn0, wm1, bm1,
                                    msg0h, x1, xi1, xj1);
  k_mid  <<<rows, 256, 0, stream>>>(ei, weT1, weT2, xi1, xj1, x1,
                                    wn1, bn1, wm2, bm2,
                                    msg0h, xi2, xj2);
  k_fin  <<<rows, 256, 0, stream>>>(ei, msg0h, xi2, xj2, rsum);
  k_head <<<B,    128, 0, stream>>>(rsum, wh1, bh1, wh2, bh2, wh3, bh3, out);
}